// Round 1
// baseline (1697.946 us; speedup 1.0000x reference)
//
#include <hip/hip_runtime.h>
#include <math.h>

#define HID 4096
#define CDIM 256
#define KCB 4096
#define NTOK 16384
#define BK 32

// ---------------- ws layout (floats) ----------------
// z:       [0, 4194304)
// e2:      [4194304, 4198400)
// idx_i32: [4198400, 4214784)   (int32)
// logz:    [4214784]
// part:    [4214785, 4215809)
#define Z_OFF    0
#define E2_OFF   4194304
#define IDX_OFF  4198400
#define LOGZ_OFF 4214784
#define PART_OFF 4214785

// d_out layout (floats): embed_hat [0,67108864) | bits | vq_loss | idx(float) x 16384
#define OUT_BITS 67108864
#define OUT_VQ   67108865
#define OUT_IDX  67108866

// ---------------- small kernels ----------------

__global__ void k_e2(const float* __restrict__ cb, float* __restrict__ e2) {
  int row = blockIdx.x * 4 + (threadIdx.x >> 6);
  int lane = threadIdx.x & 63;
  float4 v = ((const float4*)(cb + (size_t)row * CDIM))[lane];
  float s = v.x * v.x + v.y * v.y + v.z * v.z + v.w * v.w;
#pragma unroll
  for (int off = 32; off; off >>= 1) s += __shfl_down(s, off, 64);
  if (lane == 0) e2[row] = s;
}

__global__ void k_logz(const float* __restrict__ pl, float* __restrict__ logz) {
  __shared__ float red[8];
  int t = threadIdx.x;
  float mx = -INFINITY;
  for (int q = t; q < KCB; q += 256) mx = fmaxf(mx, pl[q]);
#pragma unroll
  for (int off = 32; off; off >>= 1) mx = fmaxf(mx, __shfl_down(mx, off, 64));
  if ((t & 63) == 0) red[t >> 6] = mx;
  __syncthreads();
  mx = fmaxf(fmaxf(red[0], red[1]), fmaxf(red[2], red[3]));
  float s = 0.f;
  for (int q = t; q < KCB; q += 256) s += expf(pl[q] - mx);
#pragma unroll
  for (int off = 32; off; off >>= 1) s += __shfl_down(s, off, 64);
  if ((t & 63) == 0) red[4 + (t >> 6)] = s;
  __syncthreads();
  if (t == 0) logz[0] = mx + logf(red[4] + red[5] + red[6] + red[7]);
}

// ---------------- GEMM1: z = embed @ W_pre^T + b_pre ----------------
// C[M=16384, N=256], K=4096. Tile 64x128, 256 thr, thread 4x8.

__launch_bounds__(256)
__global__ void k_gemm_pre(const float* __restrict__ A, const float* __restrict__ Bm,
                           const float* __restrict__ bias, float* __restrict__ Cm) {
  __shared__ float As[BK][68];
  __shared__ float Bs[BK][132];
  int m0 = blockIdx.x * 64;
  int n0 = blockIdx.y * 128;
  int t = threadIdx.x;
  int tx = t & 15, ty = t >> 4;
  float acc[4][8];
#pragma unroll
  for (int i = 0; i < 4; ++i)
#pragma unroll
    for (int j = 0; j < 8; ++j) acc[i][j] = 0.f;

  for (int k0 = 0; k0 < HID; k0 += BK) {
#pragma unroll
    for (int s = 0; s < 2; ++s) {
      int e = t + s * 256;
      int row = e >> 3, c4 = (e & 7) << 2;
      float4 v = *(const float4*)(A + (size_t)(m0 + row) * HID + k0 + c4);
      As[c4 + 0][row] = v.x; As[c4 + 1][row] = v.y;
      As[c4 + 2][row] = v.z; As[c4 + 3][row] = v.w;
    }
#pragma unroll
    for (int s = 0; s < 4; ++s) {
      int e = t + s * 256;
      int row = e >> 3, c4 = (e & 7) << 2;
      float4 v = *(const float4*)(Bm + (size_t)(n0 + row) * HID + k0 + c4);
      Bs[c4 + 0][row] = v.x; Bs[c4 + 1][row] = v.y;
      Bs[c4 + 2][row] = v.z; Bs[c4 + 3][row] = v.w;
    }
    __syncthreads();
#pragma unroll
    for (int kk = 0; kk < BK; ++kk) {
      float4 a  = *(const float4*)&As[kk][4 * ty];
      float4 b0 = *(const float4*)&Bs[kk][8 * tx];
      float4 b1 = *(const float4*)&Bs[kk][8 * tx + 4];
      float av[4] = {a.x, a.y, a.z, a.w};
      float bv[8] = {b0.x, b0.y, b0.z, b0.w, b1.x, b1.y, b1.z, b1.w};
#pragma unroll
      for (int i = 0; i < 4; ++i)
#pragma unroll
        for (int j = 0; j < 8; ++j) acc[i][j] = fmaf(av[i], bv[j], acc[i][j]);
    }
    __syncthreads();
  }
#pragma unroll
  for (int i = 0; i < 4; ++i) {
    int m = m0 + 4 * ty + i;
#pragma unroll
    for (int jj = 0; jj < 2; ++jj) {
      int n = n0 + 8 * tx + 4 * jj;
      float4 bv = *(const float4*)(bias + n);
      float4 o;
      o.x = acc[i][4 * jj + 0] + bv.x;
      o.y = acc[i][4 * jj + 1] + bv.y;
      o.z = acc[i][4 * jj + 2] + bv.z;
      o.w = acc[i][4 * jj + 3] + bv.w;
      *(float4*)(Cm + (size_t)m * CDIM + n) = o;
    }
  }
}

// ---------------- GEMM2: fused dist + argmin ----------------
// Per block: 64 rows of z, scans all K=4096 codes. 512 thr, thread 2x8.
// dist mimics numpy fp32: (x2 + e2[k]) - 2*xe, tie -> lowest k.

__launch_bounds__(512)
__global__ void k_argmin(const float* __restrict__ Z, const float* __restrict__ CB,
                         const float* __restrict__ e2, int* __restrict__ idx_out,
                         float* __restrict__ idx_f) {
  __shared__ float As[BK][68];
  __shared__ float Bs[BK][132];
  __shared__ float x2s[64];
  int m0 = blockIdx.x * 64;
  int t = threadIdx.x;
  {
    int r = t >> 3, p = t & 7;
    const float4* zr = (const float4*)(Z + (size_t)(m0 + r) * CDIM);
    float s = 0.f;
#pragma unroll
    for (int q = 0; q < 8; ++q) {
      float4 v = zr[p * 8 + q];
      s += v.x * v.x + v.y * v.y + v.z * v.z + v.w * v.w;
    }
#pragma unroll
    for (int off = 4; off; off >>= 1) s += __shfl_down(s, off, 8);
    if (p == 0) x2s[r] = s;
  }
  __syncthreads();
  int tx = t & 15, ty = t >> 4;  // ty in [0,32)
  float bestv[2] = {INFINITY, INFINITY};
  int besti[2] = {0, 0};
  for (int nt = 0; nt < KCB / 128; ++nt) {
    int n0 = nt * 128;
    float acc[2][8];
#pragma unroll
    for (int i = 0; i < 2; ++i)
#pragma unroll
      for (int j = 0; j < 8; ++j) acc[i][j] = 0.f;
    for (int k0 = 0; k0 < CDIM; k0 += BK) {
      {
        int row = t >> 3, c4 = (t & 7) << 2;
        float4 v = *(const float4*)(Z + (size_t)(m0 + row) * CDIM + k0 + c4);
        As[c4 + 0][row] = v.x; As[c4 + 1][row] = v.y;
        As[c4 + 2][row] = v.z; As[c4 + 3][row] = v.w;
      }
#pragma unroll
      for (int s2 = 0; s2 < 2; ++s2) {
        int e = t + s2 * 512;
        int row = e >> 3, c4 = (e & 7) << 2;
        float4 v = *(const float4*)(CB + (size_t)(n0 + row) * CDIM + k0 + c4);
        Bs[c4 + 0][row] = v.x; Bs[c4 + 1][row] = v.y;
        Bs[c4 + 2][row] = v.z; Bs[c4 + 3][row] = v.w;
      }
      __syncthreads();
#pragma unroll
      for (int kk = 0; kk < BK; ++kk) {
        float2 a  = *(const float2*)&As[kk][2 * ty];
        float4 b0 = *(const float4*)&Bs[kk][8 * tx];
        float4 b1 = *(const float4*)&Bs[kk][8 * tx + 4];
        float av[2] = {a.x, a.y};
        float bv[8] = {b0.x, b0.y, b0.z, b0.w, b1.x, b1.y, b1.z, b1.w};
#pragma unroll
        for (int i = 0; i < 2; ++i)
#pragma unroll
          for (int j = 0; j < 8; ++j) acc[i][j] = fmaf(av[i], bv[j], acc[i][j]);
      }
      __syncthreads();
    }
#pragma unroll
    for (int i = 0; i < 2; ++i) {
      float x2v = x2s[2 * ty + i];
#pragma unroll
      for (int j = 0; j < 8; ++j) {
        int k = n0 + 8 * tx + j;
        // replicate numpy fp32 elementwise: (x2 + e2) - 2*xe, no contraction
        float s = __fsub_rn(__fadd_rn(x2v, e2[k]), __fmul_rn(2.0f, acc[i][j]));
        if (s < bestv[i]) { bestv[i] = s; besti[i] = k; }  // ascending k: strict < keeps first
      }
    }
  }
#pragma unroll
  for (int i = 0; i < 2; ++i) {
    float v = bestv[i]; int bi = besti[i];
#pragma unroll
    for (int off = 8; off; off >>= 1) {
      float ov = __shfl_down(v, off, 16);
      int oi = __shfl_down(bi, off, 16);
      if (ov < v || (ov == v && oi < bi)) { v = ov; bi = oi; }
    }
    if (tx == 0) {
      int m = m0 + 2 * ty + i;
      idx_out[m] = bi;
      idx_f[m] = (float)bi;
    }
  }
}

// ---------------- GEMM3: embed_hat = codebook[idx] @ W_post^T + b_post ----------------

__launch_bounds__(256)
__global__ void k_gemm_post(const float* __restrict__ CB, const int* __restrict__ idx,
                            const float* __restrict__ Bm, const float* __restrict__ bias,
                            float* __restrict__ out) {
  __shared__ float As[BK][68];
  __shared__ float Bs[BK][132];
  __shared__ int idxs[64];
  int m0 = blockIdx.x * 64;
  int n0 = blockIdx.y * 128;
  int t = threadIdx.x;
  if (t < 64) idxs[t] = idx[m0 + t];
  __syncthreads();
  int tx = t & 15, ty = t >> 4;
  float acc[4][8];
#pragma unroll
  for (int i = 0; i < 4; ++i)
#pragma unroll
    for (int j = 0; j < 8; ++j) acc[i][j] = 0.f;

  for (int k0 = 0; k0 < CDIM; k0 += BK) {
#pragma unroll
    for (int s = 0; s < 2; ++s) {
      int e = t + s * 256;
      int row = e >> 3, c4 = (e & 7) << 2;
      float4 v = *(const float4*)(CB + (size_t)idxs[row] * CDIM + k0 + c4);
      As[c4 + 0][row] = v.x; As[c4 + 1][row] = v.y;
      As[c4 + 2][row] = v.z; As[c4 + 3][row] = v.w;
    }
#pragma unroll
    for (int s = 0; s < 4; ++s) {
      int e = t + s * 256;
      int row = e >> 3, c4 = (e & 7) << 2;
      float4 v = *(const float4*)(Bm + (size_t)(n0 + row) * CDIM + k0 + c4);
      Bs[c4 + 0][row] = v.x; Bs[c4 + 1][row] = v.y;
      Bs[c4 + 2][row] = v.z; Bs[c4 + 3][row] = v.w;
    }
    __syncthreads();
#pragma unroll
    for (int kk = 0; kk < BK; ++kk) {
      float4 a  = *(const float4*)&As[kk][4 * ty];
      float4 b0 = *(const float4*)&Bs[kk][8 * tx];
      float4 b1 = *(const float4*)&Bs[kk][8 * tx + 4];
      float av[4] = {a.x, a.y, a.z, a.w};
      float bv[8] = {b0.x, b0.y, b0.z, b0.w, b1.x, b1.y, b1.z, b1.w};
#pragma unroll
      for (int i = 0; i < 4; ++i)
#pragma unroll
        for (int j = 0; j < 8; ++j) acc[i][j] = fmaf(av[i], bv[j], acc[i][j]);
    }
    __syncthreads();
  }
#pragma unroll
  for (int i = 0; i < 4; ++i) {
    int m = m0 + 4 * ty + i;
#pragma unroll
    for (int jj = 0; jj < 2; ++jj) {
      int n = n0 + 8 * tx + 4 * jj;
      float4 bv = *(const float4*)(bias + n);
      float4 o;
      o.x = acc[i][4 * jj + 0] + bv.x;
      o.y = acc[i][4 * jj + 1] + bv.y;
      o.z = acc[i][4 * jj + 2] + bv.z;
      o.w = acc[i][4 * jj + 3] + bv.w;
      *(float4*)(out + (size_t)m * HID + n) = o;
    }
  }
}

// ---------------- losses ----------------

__global__ void k_loss(const float* __restrict__ Z, const float* __restrict__ CB,
                       const int* __restrict__ idx, float* __restrict__ part) {
  __shared__ float red[4];
  int t = threadIdx.x;
  int g = blockIdx.x * 256 + t;
  int n = g >> 4;
  int d0 = (g & 15) << 4;
  const float4* zp = (const float4*)(Z + (size_t)n * CDIM + d0);
  const float4* cp = (const float4*)(CB + (size_t)idx[n] * CDIM + d0);
  float s = 0.f;
#pragma unroll
  for (int q = 0; q < 4; ++q) {
    float4 a = zp[q], b = cp[q];
    float dx = a.x - b.x, dy = a.y - b.y, dz = a.z - b.z, dw = a.w - b.w;
    s += dx * dx + dy * dy + dz * dz + dw * dw;
  }
#pragma unroll
  for (int off = 32; off; off >>= 1) s += __shfl_down(s, off, 64);
  if ((t & 63) == 0) red[t >> 6] = s;
  __syncthreads();
  if (t == 0) part[blockIdx.x] = red[0] + red[1] + red[2] + red[3];
}

__global__ void k_final(const float* __restrict__ part, const int* __restrict__ idx,
                        const float* __restrict__ pl, const float* __restrict__ logz,
                        float* __restrict__ bits_out, float* __restrict__ vq_out) {
  __shared__ float red[8];
  int t = threadIdx.x;
  float s = 0.f;
  for (int q = t; q < 1024; q += 256) s += part[q];
#pragma unroll
  for (int off = 32; off; off >>= 1) s += __shfl_down(s, off, 64);
  if ((t & 63) == 0) red[t >> 6] = s;
  __syncthreads();
  float S = red[0] + red[1] + red[2] + red[3];
  float lz = logz[0];
  float b = 0.f;
  for (int q = t; q < NTOK; q += 256) b += (lz - pl[idx[q]]);
#pragma unroll
  for (int off = 32; off; off >>= 1) b += __shfl_down(b, off, 64);
  if ((t & 63) == 0) red[4 + (t >> 6)] = b;
  __syncthreads();
  if (t == 0) {
    float Bsum = red[4] + red[5] + red[6] + red[7];
    float m = S / 4194304.0f;  // mean((z_q - z)^2); loss_cb == loss_commit numerically
    vq_out[0] = __fadd_rn(m, __fmul_rn(0.25f, m));
    bits_out[0] = Bsum / 0.69314718055994531f;
  }
}

// ---------------- launch ----------------

extern "C" void kernel_launch(void* const* d_in, const int* in_sizes, int n_in,
                              void* d_out, int out_size, void* d_ws, size_t ws_size,
                              hipStream_t stream) {
  const float* embed    = (const float*)d_in[0];
  const float* W_pre    = (const float*)d_in[1];
  const float* b_pre    = (const float*)d_in[2];
  const float* codebook = (const float*)d_in[3];
  const float* W_post   = (const float*)d_in[4];
  const float* b_post   = (const float*)d_in[5];
  const float* prior    = (const float*)d_in[6];

  float* out = (float*)d_out;
  float* ws  = (float*)d_ws;
  float* z    = ws + Z_OFF;
  float* e2   = ws + E2_OFF;
  int*   idxw = (int*)(ws + IDX_OFF);
  float* logz = ws + LOGZ_OFF;
  float* part = ws + PART_OFF;

  k_e2<<<dim3(1024), dim3(256), 0, stream>>>(codebook, e2);
  k_logz<<<dim3(1), dim3(256), 0, stream>>>(prior, logz);
  k_gemm_pre<<<dim3(256, 2), dim3(256), 0, stream>>>(embed, W_pre, b_pre, z);
  k_argmin<<<dim3(256), dim3(512), 0, stream>>>(z, codebook, e2, idxw, out + OUT_IDX);
  k_gemm_post<<<dim3(256, 32), dim3(256), 0, stream>>>(codebook, idxw, W_post, b_post, out);
  k_loss<<<dim3(1024), dim3(256), 0, stream>>>(z, codebook, idxw, part);
  k_final<<<dim3(1), dim3(256), 0, stream>>>(part, idxw, prior, logz,
                                             out + OUT_BITS, out + OUT_VQ);
}